// Round 1
// baseline (1116.157 us; speedup 1.0000x reference)
//
#include <hip/hip_runtime.h>
#include <math.h>

// Problem constants (fixed by the reference)
#define B_  2
#define S_  2048
#define D_  1024
#define H_  16
#define HD_ 64
#define BS_ (B_ * S_)          // 4096 token rows
// SCALE = sqrt(64) = 8  -> multiply scores by 0.125f

// ---------------------------------------------------------------------------
// GEMM: C[M,N] = A[M,K] @ B[K,N] + bias[N]    (row-major, fp32)
// 128x128 tile, BK=8, 256 threads, 8x8 micro-tile per thread.
// ---------------------------------------------------------------------------
template <int BM, int BN, int BK>
__global__ __launch_bounds__(256) void gemm_bias_f32(
    const float* __restrict__ A, const float* __restrict__ Bm,
    const float* __restrict__ bias, float* __restrict__ C,
    int M, int N, int K)
{
    __shared__ float As[BK][BM];   // A stored K-major: As[k][m]
    __shared__ float Bs[BK][BN];   // B natural:       Bs[k][n]

    const int tid = threadIdx.x;
    const int tx = tid & 15;       // 16 thread cols (N)
    const int ty = tid >> 4;       // 16 thread rows (M)
    const int row0 = blockIdx.y * BM;
    const int col0 = blockIdx.x * BN;

    // loader mapping
    const int ar = tid >> 1;            // 0..127  (A row within tile)
    const int ak = (tid & 1) * 4;       // 0 or 4  (A k within tile)
    const int bk = tid >> 5;            // 0..7    (B k within tile)
    const int bc = (tid & 31) * 4;      // 0..124  (B col within tile)

    float acc[8][8];
#pragma unroll
    for (int i = 0; i < 8; ++i)
#pragma unroll
        for (int j = 0; j < 8; ++j) acc[i][j] = 0.f;

    for (int kt = 0; kt < K; kt += BK) {
        const float4 a4 = *reinterpret_cast<const float4*>(
            A + (size_t)(row0 + ar) * K + kt + ak);
        const float4 b4 = *reinterpret_cast<const float4*>(
            Bm + (size_t)(kt + bk) * N + col0 + bc);
        __syncthreads();   // previous tile's compute reads done
        As[ak + 0][ar] = a4.x;
        As[ak + 1][ar] = a4.y;
        As[ak + 2][ar] = a4.z;
        As[ak + 3][ar] = a4.w;
        *reinterpret_cast<float4*>(&Bs[bk][bc]) = b4;
        __syncthreads();

#pragma unroll
        for (int kk = 0; kk < BK; ++kk) {
            const float4 a0 = *reinterpret_cast<const float4*>(&As[kk][ty * 8]);
            const float4 a1 = *reinterpret_cast<const float4*>(&As[kk][ty * 8 + 4]);
            const float4 b0 = *reinterpret_cast<const float4*>(&Bs[kk][tx * 8]);
            const float4 b1 = *reinterpret_cast<const float4*>(&Bs[kk][tx * 8 + 4]);
            const float av[8] = {a0.x, a0.y, a0.z, a0.w, a1.x, a1.y, a1.z, a1.w};
            const float bv[8] = {b0.x, b0.y, b0.z, b0.w, b1.x, b1.y, b1.z, b1.w};
#pragma unroll
            for (int i = 0; i < 8; ++i)
#pragma unroll
                for (int j = 0; j < 8; ++j)
                    acc[i][j] = fmaf(av[i], bv[j], acc[i][j]);
        }
    }

    // epilogue: add bias, store
    const float4 bb0 = *reinterpret_cast<const float4*>(bias + col0 + tx * 8);
    const float4 bb1 = *reinterpret_cast<const float4*>(bias + col0 + tx * 8 + 4);
    const float badd[8] = {bb0.x, bb0.y, bb0.z, bb0.w, bb1.x, bb1.y, bb1.z, bb1.w};
#pragma unroll
    for (int i = 0; i < 8; ++i) {
        const int r = row0 + ty * 8 + i;
        float* crow = C + (size_t)r * N + col0 + tx * 8;
        float4 o0, o1;
        o0.x = acc[i][0] + badd[0]; o0.y = acc[i][1] + badd[1];
        o0.z = acc[i][2] + badd[2]; o0.w = acc[i][3] + badd[3];
        o1.x = acc[i][4] + badd[4]; o1.y = acc[i][5] + badd[5];
        o1.z = acc[i][6] + badd[6]; o1.w = acc[i][7] + badd[7];
        *reinterpret_cast<float4*>(crow)     = o0;
        *reinterpret_cast<float4*>(crow + 4) = o1;
    }
}

// ---------------------------------------------------------------------------
// Flash attention fp32.
// grid: (S/128, H, B). 256 threads. Q tile = 128 rows, K/V tile = 64.
// Thread (ty,tx): 8 q-rows (ty*8..), 4 key-cols / v-dims (tx*4..).
// qkv layout: row = token (b*S + s), cols: q @ h*64, k @ 1024+h*64, v @ 2048+h*64
// out: [B*S, D] with head h at column h*64.
// ---------------------------------------------------------------------------
__global__ __launch_bounds__(256) void flash_attn_f32(
    const float* __restrict__ qkv, const float* __restrict__ mask,
    float* __restrict__ out)
{
    constexpr int TR = 128;   // q rows per block
    constexpr int TC = 64;    // kv tile

    __shared__ float Qt[HD_][TR];   // [d][q]   transposed
    __shared__ float Kt[HD_][TC];   // [d][k]   transposed
    __shared__ float Vs[TC][HD_];   // [k][vd]  natural
    __shared__ float Pt[TC][TR];    // [k][q]   transposed P

    const int tid = threadIdx.x;
    const int tx = tid & 15;
    const int ty = tid >> 4;
    const int b  = blockIdx.z;
    const int h  = blockIdx.y;
    const int q0 = blockIdx.x * TR;

    const size_t rowstride = 3 * (size_t)D_;
    const float* qbase = qkv + (size_t)b * S_ * rowstride + (size_t)h * HD_;
    const float* kbase = qbase + D_;
    const float* vbase = qbase + 2 * D_;
    const float* mrow  = mask + (size_t)b * S_;

    // --- load Q tile transposed (128 tokens x 64 dims) ---
    {
        const int t0 = tid >> 4;            // 0..15
        const int d0 = (tid & 15) * 4;      // 0..60
#pragma unroll
        for (int p = 0; p < 8; ++p) {
            const int tok = t0 + p * 16;
            const float4 q4 = *reinterpret_cast<const float4*>(
                qbase + (size_t)(q0 + tok) * rowstride + d0);
            Qt[d0 + 0][tok] = q4.x;
            Qt[d0 + 1][tok] = q4.y;
            Qt[d0 + 2][tok] = q4.z;
            Qt[d0 + 3][tok] = q4.w;
        }
    }

    float m_i[8], l_i[8], o[8][4];
#pragma unroll
    for (int i = 0; i < 8; ++i) {
        m_i[i] = -1e30f;
        l_i[i] = 0.f;
#pragma unroll
        for (int j = 0; j < 4; ++j) o[i][j] = 0.f;
    }

    for (int kt = 0; kt < S_; kt += TC) {
        __syncthreads();   // previous tile fully consumed (also covers Q load on iter 0)
        // --- load K (transposed) and V (natural) tiles ---
        {
            const int t0 = tid >> 4;
            const int d0 = (tid & 15) * 4;
#pragma unroll
            for (int p = 0; p < 4; ++p) {
                const int tok = t0 + p * 16;
                const float4 k4 = *reinterpret_cast<const float4*>(
                    kbase + (size_t)(kt + tok) * rowstride + d0);
                const float4 v4 = *reinterpret_cast<const float4*>(
                    vbase + (size_t)(kt + tok) * rowstride + d0);
                Kt[d0 + 0][tok] = k4.x;
                Kt[d0 + 1][tok] = k4.y;
                Kt[d0 + 2][tok] = k4.z;
                Kt[d0 + 3][tok] = k4.w;
                *reinterpret_cast<float4*>(&Vs[tok][d0]) = v4;
            }
        }
        __syncthreads();

        // --- S = (Q K^T) * 0.125 + mask ---
        float s[8][4];
#pragma unroll
        for (int i = 0; i < 8; ++i)
#pragma unroll
            for (int j = 0; j < 4; ++j) s[i][j] = 0.f;

#pragma unroll 8
        for (int d = 0; d < HD_; ++d) {
            const float4 a0 = *reinterpret_cast<const float4*>(&Qt[d][ty * 8]);
            const float4 a1 = *reinterpret_cast<const float4*>(&Qt[d][ty * 8 + 4]);
            const float4 b0 = *reinterpret_cast<const float4*>(&Kt[d][tx * 4]);
            const float av[8] = {a0.x, a0.y, a0.z, a0.w, a1.x, a1.y, a1.z, a1.w};
            const float bv[4] = {b0.x, b0.y, b0.z, b0.w};
#pragma unroll
            for (int i = 0; i < 8; ++i)
#pragma unroll
                for (int j = 0; j < 4; ++j)
                    s[i][j] = fmaf(av[i], bv[j], s[i][j]);
        }

        float mk[4];
#pragma unroll
        for (int j = 0; j < 4; ++j) mk[j] = mrow[kt + tx * 4 + j];
#pragma unroll
        for (int i = 0; i < 8; ++i)
#pragma unroll
            for (int j = 0; j < 4; ++j)
                s[i][j] = s[i][j] * 0.125f + mk[j];

        // --- online softmax (row stats replicated across the 16 tx lanes) ---
#pragma unroll
        for (int i = 0; i < 8; ++i) {
            float rowmax = fmaxf(fmaxf(s[i][0], s[i][1]), fmaxf(s[i][2], s[i][3]));
            rowmax = fmaxf(rowmax, __shfl_xor(rowmax, 1, 16));
            rowmax = fmaxf(rowmax, __shfl_xor(rowmax, 2, 16));
            rowmax = fmaxf(rowmax, __shfl_xor(rowmax, 4, 16));
            rowmax = fmaxf(rowmax, __shfl_xor(rowmax, 8, 16));
            const float mnew = fmaxf(m_i[i], rowmax);
            const float corr = __expf(m_i[i] - mnew);
            m_i[i] = mnew;
            float rs = 0.f;
#pragma unroll
            for (int j = 0; j < 4; ++j) {
                s[i][j] = __expf(s[i][j] - mnew);
                rs += s[i][j];
            }
            rs += __shfl_xor(rs, 1, 16);
            rs += __shfl_xor(rs, 2, 16);
            rs += __shfl_xor(rs, 4, 16);
            rs += __shfl_xor(rs, 8, 16);
            l_i[i] = l_i[i] * corr + rs;
#pragma unroll
            for (int j = 0; j < 4; ++j) o[i][j] *= corr;
        }

        // --- stash P transposed for the PV pass ---
#pragma unroll
        for (int i = 0; i < 8; ++i)
#pragma unroll
            for (int j = 0; j < 4; ++j)
                Pt[tx * 4 + j][ty * 8 + i] = s[i][j];
        __syncthreads();

        // --- O += P @ V ---
#pragma unroll 8
        for (int k = 0; k < TC; ++k) {
            const float4 a0 = *reinterpret_cast<const float4*>(&Pt[k][ty * 8]);
            const float4 a1 = *reinterpret_cast<const float4*>(&Pt[k][ty * 8 + 4]);
            const float4 b0 = *reinterpret_cast<const float4*>(&Vs[k][tx * 4]);
            const float av[8] = {a0.x, a0.y, a0.z, a0.w, a1.x, a1.y, a1.z, a1.w};
            const float bv[4] = {b0.x, b0.y, b0.z, b0.w};
#pragma unroll
            for (int i = 0; i < 8; ++i)
#pragma unroll
                for (int j = 0; j < 4; ++j)
                    o[i][j] = fmaf(av[i], bv[j], o[i][j]);
        }
    }

    // --- epilogue: divide by l, merge heads ---
#pragma unroll
    for (int i = 0; i < 8; ++i) {
        const float inv = 1.0f / l_i[i];
        const int token = b * S_ + q0 + ty * 8 + i;
        float4 o4;
        o4.x = o[i][0] * inv; o4.y = o[i][1] * inv;
        o4.z = o[i][2] * inv; o4.w = o[i][3] * inv;
        *reinterpret_cast<float4*>(out + (size_t)token * D_ + h * HD_ + tx * 4) = o4;
    }
}

// ---------------------------------------------------------------------------
extern "C" void kernel_launch(void* const* d_in, const int* in_sizes, int n_in,
                              void* d_out, int out_size, void* d_ws, size_t ws_size,
                              hipStream_t stream)
{
    const float* x      = (const float*)d_in[0];   // [2,2048,1024]
    const float* amask  = (const float*)d_in[1];   // [2,2048]
    const float* w_attn = (const float*)d_in[2];   // [1024,3072]
    const float* b_attn = (const float*)d_in[3];   // [3072]
    const float* w_proj = (const float*)d_in[4];   // [1024,1024]
    const float* b_proj = (const float*)d_in[5];   // [1024]
    float* out = (float*)d_out;                    // [2,2048,1024]

    float* qkvbuf  = (float*)d_ws;                          // [4096,3072]
    float* attnout = qkvbuf + (size_t)BS_ * 3 * D_;         // [4096,1024]

    // 1) QKV projection: [4096,1024] @ [1024,3072] + bias
    gemm_bias_f32<128, 128, 8><<<dim3(3 * D_ / 128, BS_ / 128), 256, 0, stream>>>(
        x, w_attn, b_attn, qkvbuf, BS_, 3 * D_, D_);

    // 2) Flash attention
    flash_attn_f32<<<dim3(S_ / 128, H_, B_), 256, 0, stream>>>(
        qkvbuf, amask, attnout);

    // 3) Output projection: [4096,1024] @ [1024,1024] + bias
    gemm_bias_f32<128, 128, 8><<<dim3(D_ / 128, BS_ / 128), 256, 0, stream>>>(
        attnout, w_proj, b_proj, out, BS_, D_, D_);
}

// Round 2
// 600.281 us; speedup vs baseline: 1.8594x; 1.8594x over previous
//
#include <hip/hip_runtime.h>
#include <math.h>

#define B_  2
#define S_  2048
#define D_  1024
#define H_  16
#define HD_ 64
#define BS_ (B_ * S_)          // 4096 token rows

typedef float f32x4 __attribute__((ext_vector_type(4)));
typedef int   i32x4 __attribute__((ext_vector_type(4)));

__device__ __forceinline__ float bf2f(unsigned short u) {
    union { unsigned int i; float f; } c; c.i = ((unsigned int)u) << 16; return c.f;
}
__device__ __forceinline__ unsigned short f2bf(float f) {
    union { float f; unsigned int i; } c; c.f = f;
    unsigned int r = c.i + 0x7FFFu + ((c.i >> 16) & 1u);
    return (unsigned short)(r >> 16);
}

__device__ __forceinline__ void gl_lds16(const void* g, void* l) {
    __builtin_amdgcn_global_load_lds((const __attribute__((address_space(1))) void*)g,
                                     (__attribute__((address_space(3))) void*)l, 16, 0, 0);
}

__device__ __forceinline__ void mfma_bf16(f32x4& d, i32x4 a, i32x4 b) {
    asm volatile("v_mfma_f32_16x16x32_bf16 %0, %1, %2, %0" : "+v"(d) : "v"(a), "v"(b));
}

// ---------------------------------------------------------------------------
// elementwise fp32 -> bf16 (8 elems/thread)
// ---------------------------------------------------------------------------
__global__ __launch_bounds__(256) void convert_f32_bf16(
    const float* __restrict__ in, unsigned short* __restrict__ out, int n)
{
    const int i = (blockIdx.x * 256 + threadIdx.x) * 8;
    if (i >= n) return;
    const float4 a = *reinterpret_cast<const float4*>(in + i);
    const float4 b = *reinterpret_cast<const float4*>(in + i + 4);
    ushort4 u0 = make_ushort4(f2bf(a.x), f2bf(a.y), f2bf(a.z), f2bf(a.w));
    ushort4 u1 = make_ushort4(f2bf(b.x), f2bf(b.y), f2bf(b.z), f2bf(b.w));
    *reinterpret_cast<ushort4*>(out + i)     = u0;
    *reinterpret_cast<ushort4*>(out + i + 4) = u1;
}

// ---------------------------------------------------------------------------
// transpose + convert: W[K][N] fp32 -> Wt[N][K] bf16
// ---------------------------------------------------------------------------
__global__ __launch_bounds__(256) void transpose_cvt(
    const float* __restrict__ W, unsigned short* __restrict__ Wt, int K, int N)
{
    __shared__ float t[32][33];
    const int n0 = blockIdx.x * 32, k0 = blockIdx.y * 32;
    const int tx = threadIdx.x & 31, ty = threadIdx.x >> 5;   // ty 0..7
#pragma unroll
    for (int r = 0; r < 32; r += 8)
        t[ty + r][tx] = W[(size_t)(k0 + ty + r) * N + n0 + tx];
    __syncthreads();
#pragma unroll
    for (int r = 0; r < 32; r += 8)
        Wt[(size_t)(n0 + ty + r) * K + k0 + tx] = f2bf(t[tx][ty + r]);
}

// ---------------------------------------------------------------------------
// GEMM: C[M,N] = A[M,K]_bf16 * Bt[N,K]_bf16^T + bias
// 128x128 tile, BK=32, 4 waves (2x2), each wave 64x64 via 4x4 16x16x32 MFMA.
// LDS layout [kc(4)][row(128)][8elem] -> quarter-wave-contiguous ds_read_b128.
// Staged with global_load_lds width 16 (linear dest).
// ---------------------------------------------------------------------------
template <typename OutT>
__global__ __launch_bounds__(256) void gemm_bt_bf16(
    const unsigned short* __restrict__ A,   // [M][K]
    const unsigned short* __restrict__ Bt,  // [N][K]
    const float* __restrict__ bias,         // [N]
    OutT* __restrict__ C, int M, int N, int K)
{
    __shared__ alignas(16) unsigned short As[4096];  // 8 KB
    __shared__ alignas(16) unsigned short Bs[4096];  // 8 KB

    const int tid  = threadIdx.x;
    const int wave = tid >> 6;
    const int l    = tid & 63;
    const int g    = l >> 4;         // k-chunk for frags
    const int r    = l & 15;
    const int wr   = wave >> 1, wc = wave & 1;
    const int row0 = blockIdx.y * 128;
    const int col0 = blockIdx.x * 128;

    // staging: instr t covers LDS elems [(wave*2+t)*512, +512): kc=wave, row=t*64+l
    const size_t aoff0 = (size_t)(row0 +   0 + l) * K + wave * 8;
    const size_t aoff1 = (size_t)(row0 +  64 + l) * K + wave * 8;
    const size_t boff0 = (size_t)(col0 +   0 + l) * K + wave * 8;
    const size_t boff1 = (size_t)(col0 +  64 + l) * K + wave * 8;

    f32x4 acc[4][4];
#pragma unroll
    for (int mi = 0; mi < 4; ++mi)
#pragma unroll
        for (int ni = 0; ni < 4; ++ni) acc[mi][ni] = (f32x4)0.f;

    for (int kt = 0; kt < K; kt += 32) {
        __syncthreads();
        gl_lds16(A  + aoff0 + kt, As + wave * 1024);
        gl_lds16(A  + aoff1 + kt, As + wave * 1024 + 512);
        gl_lds16(Bt + boff0 + kt, Bs + wave * 1024);
        gl_lds16(Bt + boff1 + kt, Bs + wave * 1024 + 512);
        __syncthreads();

        const unsigned short* Ab = As + g * 1024;
        const unsigned short* Bb = Bs + g * 1024;
        i32x4 af[4], bf[4];
#pragma unroll
        for (int mi = 0; mi < 4; ++mi)
            af[mi] = *reinterpret_cast<const i32x4*>(Ab + (wr * 64 + mi * 16 + r) * 8);
#pragma unroll
        for (int ni = 0; ni < 4; ++ni)
            bf[ni] = *reinterpret_cast<const i32x4*>(Bb + (wc * 64 + ni * 16 + r) * 8);
#pragma unroll
        for (int mi = 0; mi < 4; ++mi)
#pragma unroll
            for (int ni = 0; ni < 4; ++ni)
                mfma_bf16(acc[mi][ni], af[mi], bf[ni]);
    }

    // epilogue: D-frag element e -> (m = g*4+e within 16, n = r within 16)
#pragma unroll
    for (int ni = 0; ni < 4; ++ni) {
        const int n = col0 + wc * 64 + ni * 16 + r;
        const float bv = bias[n];
#pragma unroll
        for (int mi = 0; mi < 4; ++mi) {
#pragma unroll
            for (int e = 0; e < 4; ++e) {
                const int m = row0 + wr * 64 + mi * 16 + g * 4 + e;
                const float val = acc[mi][ni][e] + bv;
                if constexpr (sizeof(OutT) == 2)
                    C[(size_t)m * N + n] = (OutT)f2bf(val);
                else
                    C[(size_t)m * N + n] = (OutT)val;
            }
        }
    }
}

// ---------------------------------------------------------------------------
// Flash attention, fp32 VALU, bf16 in/out.
// grid (S/64, H, B), 256 threads. Q tile 64, KV tile 64.
// Thread (ty,tx): 4 q-rows (ty*4+i), 4 cols (tx*4+j).
// LDS 51 KB -> 3 blocks/CU. KP is a union: K^T in S-phase, P in PV-phase.
// ---------------------------------------------------------------------------
__global__ __launch_bounds__(256) void flash_attn_bf16(
    const unsigned short* __restrict__ qkv,  // [BS][3072]
    const float* __restrict__ mask,          // [B][S]
    unsigned short* __restrict__ out)        // [BS][1024]
{
    __shared__ float Qt[64][68];   // [d][q] transposed
    __shared__ float KP[64][68];   // S-phase: K^T [d][tok] ; PV-phase: P [q][k]
    __shared__ float Vs[64][68];   // [tok][d]

    const int tid = threadIdx.x;
    const int tx = tid & 15;
    const int ty = tid >> 4;
    const int b  = blockIdx.z;
    const int h  = blockIdx.y;
    const int q0 = blockIdx.x * 64;

    const size_t rs = 3 * (size_t)D_;
    const unsigned short* qb = qkv + (size_t)b * S_ * rs + (size_t)h * HD_;
    const unsigned short* kb = qb + D_;
    const unsigned short* vb = qb + 2 * D_;
    const float* mrow = mask + (size_t)b * S_;

    // --- Q tile transposed: lane d0=tx*4, toks ty+p*16 ---
#pragma unroll
    for (int p = 0; p < 4; ++p) {
        const int tok = ty + p * 16;
        const ushort4 u = *reinterpret_cast<const ushort4*>(
            qb + (size_t)(q0 + tok) * rs + tx * 4);
        Qt[tx * 4 + 0][tok] = bf2f(u.x);
        Qt[tx * 4 + 1][tok] = bf2f(u.y);
        Qt[tx * 4 + 2][tok] = bf2f(u.z);
        Qt[tx * 4 + 3][tok] = bf2f(u.w);
    }

    float m_i[4], l_i[4], o[4][4];
#pragma unroll
    for (int i = 0; i < 4; ++i) {
        m_i[i] = -1e30f; l_i[i] = 0.f;
#pragma unroll
        for (int j = 0; j < 4; ++j) o[i][j] = 0.f;
    }

    for (int kt = 0; kt < S_; kt += 64) {
        __syncthreads();   // prev PV done reading Vs/KP (and Q load on iter 0)
#pragma unroll
        for (int p = 0; p < 4; ++p) {
            const int tok = ty + p * 16;
            const ushort4 ku = *reinterpret_cast<const ushort4*>(
                kb + (size_t)(kt + tok) * rs + tx * 4);
            const ushort4 vu = *reinterpret_cast<const ushort4*>(
                vb + (size_t)(kt + tok) * rs + tx * 4);
            KP[tx * 4 + 0][tok] = bf2f(ku.x);
            KP[tx * 4 + 1][tok] = bf2f(ku.y);
            KP[tx * 4 + 2][tok] = bf2f(ku.z);
            KP[tx * 4 + 3][tok] = bf2f(ku.w);
            float4 vf;
            vf.x = bf2f(vu.x); vf.y = bf2f(vu.y); vf.z = bf2f(vu.z); vf.w = bf2f(vu.w);
            *reinterpret_cast<float4*>(&Vs[tok][tx * 4]) = vf;
        }
        __syncthreads();

        // --- S = Q K^T * 0.125 + mask ---
        float s[4][4];
#pragma unroll
        for (int i = 0; i < 4; ++i)
#pragma unroll
            for (int j = 0; j < 4; ++j) s[i][j] = 0.f;

#pragma unroll 8
        for (int d = 0; d < 64; ++d) {
            const float4 qv = *reinterpret_cast<const float4*>(&Qt[d][ty * 4]);
            const float4 kv = *reinterpret_cast<const float4*>(&KP[d][tx * 4]);
            const float av[4] = {qv.x, qv.y, qv.z, qv.w};
            const float bv[4] = {kv.x, kv.y, kv.z, kv.w};
#pragma unroll
            for (int i = 0; i < 4; ++i)
#pragma unroll
                for (int j = 0; j < 4; ++j)
                    s[i][j] = fmaf(av[i], bv[j], s[i][j]);
        }

        float mk[4];
#pragma unroll
        for (int j = 0; j < 4; ++j) mk[j] = mrow[kt + tx * 4 + j];
#pragma unroll
        for (int i = 0; i < 4; ++i)
#pragma unroll
            for (int j = 0; j < 4; ++j)
                s[i][j] = s[i][j] * 0.125f + mk[j];

        // --- online softmax (stats replicated across 16 tx lanes) ---
#pragma unroll
        for (int i = 0; i < 4; ++i) {
            float rowmax = fmaxf(fmaxf(s[i][0], s[i][1]), fmaxf(s[i][2], s[i][3]));
            rowmax = fmaxf(rowmax, __shfl_xor(rowmax, 1, 16));
            rowmax = fmaxf(rowmax, __shfl_xor(rowmax, 2, 16));
            rowmax = fmaxf(rowmax, __shfl_xor(rowmax, 4, 16));
            rowmax = fmaxf(rowmax, __shfl_xor(rowmax, 8, 16));
            const float mnew = fmaxf(m_i[i], rowmax);
            const float corr = __expf(m_i[i] - mnew);
            m_i[i] = mnew;
            float rsum = 0.f;
#pragma unroll
            for (int j = 0; j < 4; ++j) {
                s[i][j] = __expf(s[i][j] - mnew);
                rsum += s[i][j];
            }
            rsum += __shfl_xor(rsum, 1, 16);
            rsum += __shfl_xor(rsum, 2, 16);
            rsum += __shfl_xor(rsum, 4, 16);
            rsum += __shfl_xor(rsum, 8, 16);
            l_i[i] = l_i[i] * corr + rsum;
#pragma unroll
            for (int j = 0; j < 4; ++j) o[i][j] *= corr;
        }

        // --- P into KP union (natural [q][k], float4 writes) ---
        __syncthreads();   // all waves done reading K^T
#pragma unroll
        for (int i = 0; i < 4; ++i) {
            float4 pv;
            pv.x = s[i][0]; pv.y = s[i][1]; pv.z = s[i][2]; pv.w = s[i][3];
            *reinterpret_cast<float4*>(&KP[ty * 4 + i][tx * 4]) = pv;
        }
        __syncthreads();

        // --- O += P @ V ---
#pragma unroll 4
        for (int kc = 0; kc < 16; ++kc) {
            float4 pv[4], vv[4];
#pragma unroll
            for (int i = 0; i < 4; ++i)
                pv[i] = *reinterpret_cast<const float4*>(&KP[ty * 4 + i][kc * 4]);
#pragma unroll
            for (int c = 0; c < 4; ++c)
                vv[c] = *reinterpret_cast<const float4*>(&Vs[kc * 4 + c][tx * 4]);
#pragma unroll
            for (int i = 0; i < 4; ++i) {
                const float pa[4] = {pv[i].x, pv[i].y, pv[i].z, pv[i].w};
#pragma unroll
                for (int c = 0; c < 4; ++c) {
                    const float vb4[4] = {vv[c].x, vv[c].y, vv[c].z, vv[c].w};
#pragma unroll
                    for (int j = 0; j < 4; ++j)
                        o[i][j] = fmaf(pa[c], vb4[j], o[i][j]);
                }
            }
        }
    }

    // --- epilogue ---
#pragma unroll
    for (int i = 0; i < 4; ++i) {
        const float inv = 1.0f / l_i[i];
        const size_t token = (size_t)b * S_ + q0 + ty * 4 + i;
        ushort4 w = make_ushort4(f2bf(o[i][0] * inv), f2bf(o[i][1] * inv),
                                 f2bf(o[i][2] * inv), f2bf(o[i][3] * inv));
        *reinterpret_cast<ushort4*>(out + token * D_ + h * HD_ + tx * 4) = w;
    }
}

// ---------------------------------------------------------------------------
extern "C" void kernel_launch(void* const* d_in, const int* in_sizes, int n_in,
                              void* d_out, int out_size, void* d_ws, size_t ws_size,
                              hipStream_t stream)
{
    const float* x      = (const float*)d_in[0];   // [2,2048,1024]
    const float* amask  = (const float*)d_in[1];   // [2,2048]
    const float* w_attn = (const float*)d_in[2];   // [1024,3072]
    const float* b_attn = (const float*)d_in[3];   // [3072]
    const float* w_proj = (const float*)d_in[4];   // [1024,1024]
    const float* b_proj = (const float*)d_in[5];   // [1024]
    float* out = (float*)d_out;                    // [2,2048,1024] fp32

    unsigned short* qkvb  = (unsigned short*)d_ws;                  // [4096][3072] bf16
    unsigned short* attnb = qkvb  + (size_t)BS_ * 3 * D_;           // [4096][1024] bf16
    unsigned short* xb    = attnb + (size_t)BS_ * D_;               // [4096][1024] bf16
    unsigned short* wat   = xb    + (size_t)BS_ * D_;               // [3072][1024] bf16
    unsigned short* wpt   = wat   + (size_t)3 * D_ * D_;            // [1024][1024] bf16

    // conversions / weight transposes
    convert_f32_bf16<<<(BS_ * D_) / 2048, 256, 0, stream>>>(x, xb, BS_ * D_);
    transpose_cvt<<<dim3(3 * D_ / 32, D_ / 32), 256, 0, stream>>>(w_attn, wat, D_, 3 * D_);
    transpose_cvt<<<dim3(D_ / 32, D_ / 32), 256, 0, stream>>>(w_proj, wpt, D_, D_);

    // 1) QKV projection (bf16 MFMA) -> bf16 qkv
    gemm_bt_bf16<unsigned short><<<dim3(3 * D_ / 128, BS_ / 128), 256, 0, stream>>>(
        xb, wat, b_attn, qkvb, BS_, 3 * D_, D_);

    // 2) flash attention -> bf16
    flash_attn_bf16<<<dim3(S_ / 64, H_, B_), 256, 0, stream>>>(qkvb, amask, attnb);

    // 3) output projection (bf16 MFMA) -> fp32 out
    gemm_bt_bf16<float><<<dim3(D_ / 128, BS_ / 128), 256, 0, stream>>>(
        attnb, wpt, b_proj, out, BS_, D_, D_);
}

// Round 4
// 191.409 us; speedup vs baseline: 5.8313x; 3.1361x over previous
//
#include <hip/hip_runtime.h>
#include <math.h>

#define B_  2
#define S_  2048
#define D_  1024
#define H_  16
#define HD_ 64
#define BS_ (B_ * S_)          // 4096 token rows

typedef float f32x4 __attribute__((ext_vector_type(4)));
typedef int   i32x4 __attribute__((ext_vector_type(4)));

__device__ __forceinline__ float bf2f(unsigned short u) {
    union { unsigned int i; float f; } c; c.i = ((unsigned int)u) << 16; return c.f;
}
__device__ __forceinline__ unsigned short f2bf(float f) {
    union { float f; unsigned int i; } c; c.f = f;
    unsigned int r = c.i + 0x7FFFu + ((c.i >> 16) & 1u);
    return (unsigned short)(r >> 16);
}
__device__ __forceinline__ unsigned int cvtpk_bf16(float lo, float hi) {
    unsigned int r;
    asm volatile("v_cvt_pk_bf16_f32 %0, %1, %2" : "=v"(r) : "v"(lo), "v"(hi));
    return r;
}
__device__ __forceinline__ void gl_lds16(const void* g, void* l) {
    __builtin_amdgcn_global_load_lds((const __attribute__((address_space(1))) void*)g,
                                     (__attribute__((address_space(3))) void*)l, 16, 0, 0);
}
__device__ __forceinline__ void mfma_bf16(f32x4& d, i32x4 a, i32x4 b) {
    asm volatile("v_mfma_f32_16x16x32_bf16 %0, %1, %2, %0" : "+v"(d) : "v"(a), "v"(b));
}

// ---------------------------------------------------------------------------
// elementwise fp32 -> bf16 (8 elems/thread)
// ---------------------------------------------------------------------------
__global__ __launch_bounds__(256) void convert_f32_bf16(
    const float* __restrict__ in, unsigned short* __restrict__ out, int n)
{
    const int i = (blockIdx.x * 256 + threadIdx.x) * 8;
    if (i >= n) return;
    const float4 a = *reinterpret_cast<const float4*>(in + i);
    const float4 b = *reinterpret_cast<const float4*>(in + i + 4);
    ushort4 u0 = make_ushort4(f2bf(a.x), f2bf(a.y), f2bf(a.z), f2bf(a.w));
    ushort4 u1 = make_ushort4(f2bf(b.x), f2bf(b.y), f2bf(b.z), f2bf(b.w));
    *reinterpret_cast<ushort4*>(out + i)     = u0;
    *reinterpret_cast<ushort4*>(out + i + 4) = u1;
}

// ---------------------------------------------------------------------------
// transpose + convert: W[K][N] fp32 -> Wt[N][K] bf16
// ---------------------------------------------------------------------------
__global__ __launch_bounds__(256) void transpose_cvt(
    const float* __restrict__ W, unsigned short* __restrict__ Wt, int K, int N)
{
    __shared__ float t[32][33];
    const int n0 = blockIdx.x * 32, k0 = blockIdx.y * 32;
    const int tx = threadIdx.x & 31, ty = threadIdx.x >> 5;   // ty 0..7
#pragma unroll
    for (int r = 0; r < 32; r += 8)
        t[ty + r][tx] = W[(size_t)(k0 + ty + r) * N + n0 + tx];
    __syncthreads();
#pragma unroll
    for (int r = 0; r < 32; r += 8)
        Wt[(size_t)(n0 + ty + r) * K + k0 + tx] = f2bf(t[tx][ty + r]);
}

// ---------------------------------------------------------------------------
// GEMM: C[M,N] = A[M,K]_bf16 * Bt[N,K]_bf16^T + bias   (verified r1/r2)
// ---------------------------------------------------------------------------
template <typename OutT>
__global__ __launch_bounds__(256) void gemm_bt_bf16(
    const unsigned short* __restrict__ A,   // [M][K]
    const unsigned short* __restrict__ Bt,  // [N][K]
    const float* __restrict__ bias,         // [N]
    OutT* __restrict__ C, int M, int N, int K)
{
    __shared__ alignas(16) unsigned short As[4096];  // 8 KB
    __shared__ alignas(16) unsigned short Bs[4096];  // 8 KB

    const int tid  = threadIdx.x;
    const int wave = tid >> 6;
    const int l    = tid & 63;
    const int g    = l >> 4;
    const int r    = l & 15;
    const int wr   = wave >> 1, wc = wave & 1;
    const int row0 = blockIdx.y * 128;
    const int col0 = blockIdx.x * 128;

    const size_t aoff0 = (size_t)(row0 +   0 + l) * K + wave * 8;
    const size_t aoff1 = (size_t)(row0 +  64 + l) * K + wave * 8;
    const size_t boff0 = (size_t)(col0 +   0 + l) * K + wave * 8;
    const size_t boff1 = (size_t)(col0 +  64 + l) * K + wave * 8;

    f32x4 acc[4][4];
#pragma unroll
    for (int mi = 0; mi < 4; ++mi)
#pragma unroll
        for (int ni = 0; ni < 4; ++ni) acc[mi][ni] = (f32x4)0.f;

    for (int kt = 0; kt < K; kt += 32) {
        __syncthreads();
        gl_lds16(A  + aoff0 + kt, As + wave * 1024);
        gl_lds16(A  + aoff1 + kt, As + wave * 1024 + 512);
        gl_lds16(Bt + boff0 + kt, Bs + wave * 1024);
        gl_lds16(Bt + boff1 + kt, Bs + wave * 1024 + 512);
        __syncthreads();

        const unsigned short* Ab = As + g * 1024;
        const unsigned short* Bb = Bs + g * 1024;
        i32x4 af[4], bf[4];
#pragma unroll
        for (int mi = 0; mi < 4; ++mi)
            af[mi] = *reinterpret_cast<const i32x4*>(Ab + (wr * 64 + mi * 16 + r) * 8);
#pragma unroll
        for (int ni = 0; ni < 4; ++ni)
            bf[ni] = *reinterpret_cast<const i32x4*>(Bb + (wc * 64 + ni * 16 + r) * 8);
#pragma unroll
        for (int mi = 0; mi < 4; ++mi)
#pragma unroll
            for (int ni = 0; ni < 4; ++ni)
                mfma_bf16(acc[mi][ni], af[mi], bf[ni]);
    }

#pragma unroll
    for (int ni = 0; ni < 4; ++ni) {
        const int n = col0 + wc * 64 + ni * 16 + r;
        const float bv = bias[n];
#pragma unroll
        for (int mi = 0; mi < 4; ++mi) {
#pragma unroll
            for (int e = 0; e < 4; ++e) {
                const int m = row0 + wr * 64 + mi * 16 + g * 4 + e;
                const float val = acc[mi][ni][e] + bv;
                if constexpr (sizeof(OutT) == 2)
                    C[(size_t)m * N + n] = (OutT)f2bf(val);
                else
                    C[(size_t)m * N + n] = (OutT)val;
            }
        }
    }
}

// ---------------------------------------------------------------------------
// MFMA flash attention.
// grid (S/128, H, B), 256 threads = 4 waves, 32 q-rows per wave, KV tile 64.
// S^T = mfma(K, Q)  -> q is lane-local (col=r): softmax needs only 2 shfl_xor.
// O^T = mfma(V^T, P^T) accumulated in regs; P^T frags built via cvt_pk + shfl.
// K staged via global_load_lds w16 with source-side XOR swizzle; V^T staged
// with b16 column writes (2-way, free) using the same (row&7)<<3 XOR.
// ---------------------------------------------------------------------------
__global__ __launch_bounds__(256) void flash_attn_mfma(
    const unsigned short* __restrict__ qkv,  // [BS][3072]
    const float* __restrict__ mask,          // [B][S]
    unsigned short* __restrict__ out)        // [BS][1024]
{
    __shared__ alignas(16) unsigned short Klds[64 * 64];  // swizzled [key][d]
    __shared__ alignas(16) unsigned short Vt[64 * 64];    // swizzled [d][key]

    const int tid  = threadIdx.x;
    const int wave = tid >> 6;
    const int l    = tid & 63;
    const int g    = l >> 4;
    const int r    = l & 15;
    const int b    = blockIdx.z;
    const int h    = blockIdx.y;
    const int q0   = blockIdx.x * 128;
    const int qw   = q0 + wave * 32;          // this wave's 32 q-rows

    const size_t rs = 3 * (size_t)D_;
    const unsigned short* qb = qkv + (size_t)b * S_ * rs + (size_t)h * HD_;
    const unsigned short* kb = qb + D_;
    const unsigned short* vb = qb + 2 * D_;
    const float* mrow = mask + (size_t)b * S_;

    // --- Q fragments in registers: qf[ni][ks], q = qw + ni*16 + r, d = ks*32+g*8+j
    i32x4 qf[2][2];
#pragma unroll
    for (int ni = 0; ni < 2; ++ni)
#pragma unroll
        for (int ks = 0; ks < 2; ++ks)
            qf[ni][ks] = *reinterpret_cast<const i32x4*>(
                qb + (size_t)(qw + ni * 16 + r) * rs + ks * 32 + g * 8);

    // --- K staging source (pre-swizzled global address, linear LDS dest) ---
    // instr t of wave w: LDS ushort [w*1024 + t*512 + l*8], key = w*16+t*8+(l>>3)
    const int kkey = wave * 16 + (l >> 3);            // for t=0 (+8 for t=1)
    const int kuni = ((l & 7) ^ ((l >> 3) & 7)) * 8;  // swizzled d-offset (elems)

    // --- V staging mapping: key = wave*16 + (l>>2), part = l&3 ---
    const int vkey  = wave * 16 + (l >> 2);
    const int vpart = l & 3;

    f32x4 acc[4][2];   // O^T: d = mi*16+g*4+e, q = ni*16+r
    float m_i[2], l_i[2];
#pragma unroll
    for (int mi = 0; mi < 4; ++mi)
#pragma unroll
        for (int ni = 0; ni < 2; ++ni) acc[mi][ni] = (f32x4)0.f;
    m_i[0] = m_i[1] = -1e30f;
    l_i[0] = l_i[1] = 0.f;

    for (int kt = 0; kt < S_; kt += 64) {
        __syncthreads();   // previous tile fully consumed
        // K: 2 global_load_lds per wave
        gl_lds16(kb + (size_t)(kt + kkey) * rs + kuni,     Klds + wave * 1024);
        gl_lds16(kb + (size_t)(kt + kkey + 8) * rs + kuni, Klds + wave * 1024 + 512);
        // V^T: 4 ushort4 loads + 16 b16 writes (2-way conflicts = free)
#pragma unroll
        for (int p = 0; p < 4; ++p) {
            const int d0 = p * 16 + vpart * 4;
            const ushort4 vv = *reinterpret_cast<const ushort4*>(
                vb + (size_t)(kt + vkey) * rs + d0);
            Vt[(d0 + 0) * 64 + (vkey ^ (((d0 + 0) & 7) << 3))] = vv.x;
            Vt[(d0 + 1) * 64 + (vkey ^ (((d0 + 1) & 7) << 3))] = vv.y;
            Vt[(d0 + 2) * 64 + (vkey ^ (((d0 + 2) & 7) << 3))] = vv.z;
            Vt[(d0 + 3) * 64 + (vkey ^ (((d0 + 3) & 7) << 3))] = vv.w;
        }
        __syncthreads();

        // --- S^T = K · Q^T : s[mi][ni], key = mi*16+g*4+e (row), q = ni*16+r
        f32x4 s[4][2];
#pragma unroll
        for (int mi = 0; mi < 4; ++mi)
#pragma unroll
            for (int ni = 0; ni < 2; ++ni) s[mi][ni] = (f32x4)0.f;
#pragma unroll
        for (int ks = 0; ks < 2; ++ks) {
#pragma unroll
            for (int mi = 0; mi < 4; ++mi) {
                const i32x4 kf = *reinterpret_cast<const i32x4*>(
                    Klds + (mi * 16 + r) * 64 + ((ks * 32 + g * 8) ^ ((r & 7) << 3)));
#pragma unroll
                for (int ni = 0; ni < 2; ++ni)
                    mfma_bf16(s[mi][ni], kf, qf[ni][ks]);
            }
        }

        // --- scale + additive mask (mask indexed by key) ---
#pragma unroll
        for (int mi = 0; mi < 4; ++mi) {
            const float4 mk = *reinterpret_cast<const float4*>(
                mrow + kt + mi * 16 + g * 4);
#pragma unroll
            for (int ni = 0; ni < 2; ++ni) {
                s[mi][ni][0] = s[mi][ni][0] * 0.125f + mk.x;
                s[mi][ni][1] = s[mi][ni][1] * 0.125f + mk.y;
                s[mi][ni][2] = s[mi][ni][2] * 0.125f + mk.z;
                s[mi][ni][3] = s[mi][ni][3] * 0.125f + mk.w;
            }
        }

        // --- online softmax + pack P to bf16 pairs ---
        unsigned int pk[4][2][2];   // [mi][ni][wl]: keys (mi*16+g*4+2wl, +1)
        float corr[2];
#pragma unroll
        for (int ni = 0; ni < 2; ++ni) {
            float tmax = -1e30f;
#pragma unroll
            for (int mi = 0; mi < 4; ++mi)
#pragma unroll
                for (int e = 0; e < 4; ++e)
                    tmax = fmaxf(tmax, s[mi][ni][e]);
            tmax = fmaxf(tmax, __shfl_xor(tmax, 16));
            tmax = fmaxf(tmax, __shfl_xor(tmax, 32));
            const float mnew = fmaxf(m_i[ni], tmax);
            corr[ni] = __expf(m_i[ni] - mnew);
            m_i[ni] = mnew;
            float ls = 0.f;
#pragma unroll
            for (int mi = 0; mi < 4; ++mi) {
                float p0 = __expf(s[mi][ni][0] - mnew);
                float p1 = __expf(s[mi][ni][1] - mnew);
                float p2 = __expf(s[mi][ni][2] - mnew);
                float p3 = __expf(s[mi][ni][3] - mnew);
                ls += (p0 + p1) + (p2 + p3);
                pk[mi][ni][0] = cvtpk_bf16(p0, p1);
                pk[mi][ni][1] = cvtpk_bf16(p2, p3);
            }
            l_i[ni] = l_i[ni] * corr[ni] + ls;   // lane-partial; reduced at end
#pragma unroll
            for (int mi = 0; mi < 4; ++mi) acc[mi][ni] *= corr[ni];
        }

        // --- PV: O^T += V^T · P^T ---
#pragma unroll
        for (int ks = 0; ks < 2; ++ks) {
            // build P^T B-frags: pf[ni] word w = keys ks*32+g*8+2w,+1 of q-row
            i32x4 pf[2];
#pragma unroll
            for (int ni = 0; ni < 2; ++ni) {
#pragma unroll
                for (int w = 0; w < 4; ++w) {
                    const int src = (((g & 1) * 2 + (w >> 1)) << 4) + r;
                    const unsigned int vA = __shfl(pk[2 * ks + 0][ni][w & 1], src);
                    const unsigned int vB = __shfl(pk[2 * ks + 1][ni][w & 1], src);
                    pf[ni][w] = (int)((g >> 1) ? vB : vA);
                }
            }
#pragma unroll
            for (int mi = 0; mi < 4; ++mi) {
                const i32x4 vf = *reinterpret_cast<const i32x4*>(
                    Vt + (mi * 16 + r) * 64 + ((ks * 32 + g * 8) ^ ((r & 7) << 3)));
#pragma unroll
                for (int ni = 0; ni < 2; ++ni)
                    mfma_bf16(acc[mi][ni], vf, pf[ni]);
            }
        }
    }

    // --- epilogue: reduce l across g-lanes, divide, store bf16 ---
#pragma unroll
    for (int ni = 0; ni < 2; ++ni) {
        float lf = l_i[ni];
        lf += __shfl_xor(lf, 16);
        lf += __shfl_xor(lf, 32);
        const float inv = 1.0f / lf;
        const size_t token = (size_t)b * S_ + qw + ni * 16 + r;
#pragma unroll
        for (int mi = 0; mi < 4; ++mi) {
            const f32x4 v = acc[mi][ni] * inv;
            uint2 w;
            w.x = cvtpk_bf16(v[0], v[1]);
            w.y = cvtpk_bf16(v[2], v[3]);
            *reinterpret_cast<uint2*>(
                out + token * D_ + h * HD_ + mi * 16 + g * 4) = w;
        }
    }
}

// ---------------------------------------------------------------------------
extern "C" void kernel_launch(void* const* d_in, const int* in_sizes, int n_in,
                              void* d_out, int out_size, void* d_ws, size_t ws_size,
                              hipStream_t stream)
{
    const float* x      = (const float*)d_in[0];   // [2,2048,1024]
    const float* amask  = (const float*)d_in[1];   // [2,2048]
    const float* w_attn = (const float*)d_in[2];   // [1024,3072]
    const float* b_attn = (const float*)d_in[3];   // [3072]
    const float* w_proj = (const float*)d_in[4];   // [1024,1024]
    const float* b_proj = (const float*)d_in[5];   // [1024]
    float* out = (float*)d_out;                    // [2,2048,1024] fp32

    unsigned short* qkvb  = (unsigned short*)d_ws;                  // [4096][3072] bf16
    unsigned short* attnb = qkvb  + (size_t)BS_ * 3 * D_;           // [4096][1024] bf16
    unsigned short* xb    = attnb + (size_t)BS_ * D_;               // [4096][1024] bf16
    unsigned short* wat   = xb    + (size_t)BS_ * D_;               // [3072][1024] bf16
    unsigned short* wpt   = wat   + (size_t)3 * D_ * D_;            // [1024][1024] bf16

    convert_f32_bf16<<<(BS_ * D_) / 2048, 256, 0, stream>>>(x, xb, BS_ * D_);
    transpose_cvt<<<dim3(3 * D_ / 32, D_ / 32), 256, 0, stream>>>(w_attn, wat, D_, 3 * D_);
    transpose_cvt<<<dim3(D_ / 32, D_ / 32), 256, 0, stream>>>(w_proj, wpt, D_, D_);

    // 1) QKV projection (bf16 MFMA) -> bf16 qkv
    gemm_bt_bf16<unsigned short><<<dim3(3 * D_ / 128, BS_ / 128), 256, 0, stream>>>(
        xb, wat, b_attn, qkvb, BS_, 3 * D_, D_);

    // 2) MFMA flash attention -> bf16
    flash_attn_mfma<<<dim3(S_ / 128, H_, B_), 256, 0, stream>>>(qkvb, amask, attnb);

    // 3) output projection (bf16 MFMA) -> fp32 out
    gemm_bt_bf16<float><<<dim3(D_ / 128, BS_ / 128), 256, 0, stream>>>(
        attnb, wpt, b_proj, out, BS_, D_, D_);
}